// Round 8
// baseline (212.032 us; speedup 1.0000x reference)
//
#include <hip/hip_runtime.h>
#include <math.h>

#define N_PTS 100000
#define KDIM 128
#define CDIM 128          // IN_C == OUT_C == 128
#define TILE_N 64
#define NB1 ((N_PTS + TILE_N - 1) / TILE_N)   // 1563 C1 blocks

typedef short s16x8 __attribute__((ext_vector_type(8)));
typedef float f32x4 __attribute__((ext_vector_type(4)));

// round-to-nearest-even float -> bf16 bits
static __device__ __forceinline__ unsigned short f2bf(float f) {
    unsigned int u = __float_as_uint(f);
    unsigned int r = (u + 0x7FFFu + ((u >> 16) & 1u)) >> 16;
    return (unsigned short)r;
}
static __device__ __forceinline__ float bf2f(unsigned short h) {
    return __uint_as_float(((unsigned int)h) << 16);
}

// truncation hi/lo split (cheap; residual error ~2^-16 relative)
static __device__ __forceinline__ void split_trunc(float v, unsigned short& hi, unsigned short& lo) {
    unsigned int u = __float_as_uint(v);
    unsigned int uh = u & 0xFFFF0000u;
    float lf = v - __uint_as_float(uh);
    hi = (unsigned short)(u >> 16);
    lo = (unsigned short)(__float_as_uint(lf) >> 16);
}

// ---------------- Kernel A (MFMA v3): partials[b][k][i] = sum over block's n-chunk of U[n,k]*x[n,i]
// 512 thr = 8 waves. Staging: threads 0-255 stage U, 256-511 stage x; each thread
// loads 8 float4 (4 ch x 8 rows, 1KB/wave-inst coalesced), truncation-splits, writes
// 8 ds_write_b128 (full j-runs). XOR swizzle slot'=(c&15)^tile balances bank quads.
// Compute: wave w owns mt {(w&3)*2,+1}, nt {(w>>2)*4..+3}; 2 K=32 subchunks / 64-n chunk.
__global__ __launch_bounds__(512, 4) void kA(const float* __restrict__ U,
                                             const float* __restrict__ x,
                                             float* __restrict__ partials,
                                             int chunk) {
    __shared__ unsigned short Hs[2][8192];   // [arr][sub*4096 + granule*8 + j]
    __shared__ unsigned short Ls[2][8192];   // arr 0 = U (A-frag), 1 = x (B-frag)
    const int tid = threadIdx.x;
    const int b = blockIdx.x;
    const int n_begin = b * chunk;
    const int n_end = min(N_PTS, n_begin + chunk);
    const int lane = tid & 63;
    const int w = tid >> 6;             // wave 0..7
    const int mtb = (w & 3) * 2;        // k-tile base: 2 tiles
    const int ntb = (w >> 2) * 4;       // i-tile base: 4 tiles
    const int quad = lane >> 4;
    const int nl = lane & 15;

    // staging role
    const int arr = tid >> 8;                   // 0: U, 1: x
    const float* __restrict__ src = arr ? x : U;
    const int c4 = (tid & 31) * 4;              // 4 channels
    const int rq = (tid >> 5) & 7;              // row octet within 64-row chunk
    const int Tt = c4 >> 4;                     // channel tile 0..7
    const int ssub = rq >> 2;                   // subchunk 0..1
    const int R = rq & 3;                       // row-octet within subchunk

    f32x4 acc[2][4];
#pragma unroll
    for (int mi = 0; mi < 2; ++mi)
#pragma unroll
        for (int ni = 0; ni < 4; ++ni) acc[mi][ni] = (f32x4)(0.0f);

    for (int n0 = n_begin; n0 < n_end; n0 += 64) {
        // ---- stage: 8 float4 loads (rows rq*8..+7, channels c4..c4+3)
        float4 v[8];
#pragma unroll
        for (int jj = 0; jj < 8; ++jj) {
            int gn = n0 + rq * 8 + jj;
            v[jj] = (gn < n_end) ? *(const float4*)&src[(size_t)gn * 128 + c4]
                                 : make_float4(0, 0, 0, 0);
        }
#pragma unroll
        for (int cc = 0; cc < 4; ++cc) {
            s16x8 hh, ll;
#pragma unroll
            for (int jj = 0; jj < 8; ++jj) {
                unsigned short h, l;
                split_trunc(((const float*)&v[jj])[cc], h, l);
                hh[jj] = (short)h;
                ll[jj] = (short)l;
            }
            const int c = c4 + cc;
            const int g = Tt * 64 + R * 16 + ((c & 15) ^ Tt);   // swizzled granule
            const int dst = ssub * 4096 + g * 8;
            *(s16x8*)&Hs[arr][dst] = hh;
            *(s16x8*)&Ls[arr][dst] = ll;
        }
        __syncthreads();

        // ---- compute: 2 subchunks x 8 tiles/wave x 3-MFMA split
#pragma unroll
        for (int sub = 0; sub < 2; ++sub) {
            const int base = sub * 4096;
            s16x8 ah[2], al[2];
#pragma unroll
            for (int mi = 0; mi < 2; ++mi) {
                const int T = mtb + mi;
                const int off = base + (T * 64 + quad * 16 + (nl ^ T)) * 8;
                ah[mi] = *(s16x8*)&Hs[0][off];
                al[mi] = *(s16x8*)&Ls[0][off];
            }
#pragma unroll
            for (int ni = 0; ni < 4; ++ni) {
                const int T2 = ntb + ni;
                const int off = base + (T2 * 64 + quad * 16 + (nl ^ T2)) * 8;
                s16x8 bh = *(s16x8*)&Hs[1][off];
                s16x8 bl = *(s16x8*)&Ls[1][off];
#pragma unroll
                for (int mi = 0; mi < 2; ++mi) {
                    acc[mi][ni] = __builtin_amdgcn_mfma_f32_16x16x32_bf16(ah[mi], bh, acc[mi][ni], 0, 0, 0);
                    acc[mi][ni] = __builtin_amdgcn_mfma_f32_16x16x32_bf16(al[mi], bh, acc[mi][ni], 0, 0, 0);
                    acc[mi][ni] = __builtin_amdgcn_mfma_f32_16x16x32_bf16(ah[mi], bl, acc[mi][ni], 0, 0, 0);
                }
            }
        }
        __syncthreads();
    }

    // ---- epilogue: partials[b][k][i]; C/D layout: col(i)=nl, row(k)=quad*4+reg
    float* p = partials + (size_t)b * 16384;
#pragma unroll
    for (int mi = 0; mi < 2; ++mi) {
#pragma unroll
        for (int reg = 0; reg < 4; ++reg) {
            int k = (mtb + mi) * 16 + quad * 4 + reg;
#pragma unroll
            for (int ni = 0; ni < 4; ++ni) {
                int i = (ntb + ni) * 16 + nl;
                p[k * 128 + i] = acc[mi][ni][reg];
            }
        }
    }
}

// ---------------- Kernel A2a: partial2[s][j] = sum of partials[b][j] over this s-slice of b
__global__ __launch_bounds__(256) void kA2a(const float* __restrict__ partials,
                                            float* __restrict__ partial2, int nA) {
    const int jc = blockIdx.x >> 3;
    const int s = blockIdx.x & 7;
    const int j = jc * 256 + threadIdx.x;
    const int per = (nA + 7) >> 3;
    int b = s * per;
    const int be = min(b + per, nA);
    float a0 = 0.0f, a1 = 0.0f, a2 = 0.0f, a3 = 0.0f;
    for (; b + 4 <= be; b += 4) {
        a0 += partials[(size_t)(b + 0) * 16384 + j];
        a1 += partials[(size_t)(b + 1) * 16384 + j];
        a2 += partials[(size_t)(b + 2) * 16384 + j];
        a3 += partials[(size_t)(b + 3) * 16384 + j];
    }
    for (; b < be; ++b) a0 += partials[(size_t)b * 16384 + j];
    partial2[(size_t)s * 16384 + j] = (a0 + a1) + (a2 + a3);
}

// ---------------- Kernel B (merged kA2b): mixed[o][k] = sum_i coeffs[o][k][i]*spec[k][i]
// spec[k][i] computed inline as sum_s partial2[s][k*128+i] (L2/L3-hot).
// Emits bf16 hi/lo of mixed in A-FRAGMENT order for kC1.
__global__ __launch_bounds__(256) void kB(const float* __restrict__ coeffs,
                                          const float* __restrict__ partial2,
                                          unsigned short* __restrict__ afrag_hi,
                                          unsigned short* __restrict__ afrag_lo) {
    int wave = (blockIdx.x * 256 + threadIdx.x) >> 6;   // [0, 16384)
    int lane = threadIdx.x & 63;
    int o = wave >> 7;
    int k = wave & 127;
    const int j = k * 128 + lane * 2;
    float2 p0 = *(const float2*)&partial2[j];
    float2 p1 = *(const float2*)&partial2[16384 + j];
    float2 p2 = *(const float2*)&partial2[2 * 16384 + j];
    float2 p3 = *(const float2*)&partial2[3 * 16384 + j];
    float2 p4 = *(const float2*)&partial2[4 * 16384 + j];
    float2 p5 = *(const float2*)&partial2[5 * 16384 + j];
    float2 p6 = *(const float2*)&partial2[6 * 16384 + j];
    float2 p7 = *(const float2*)&partial2[7 * 16384 + j];
    float sx = ((p0.x + p1.x) + (p2.x + p3.x)) + ((p4.x + p5.x) + (p6.x + p7.x));
    float sy = ((p0.y + p1.y) + (p2.y + p3.y)) + ((p4.y + p5.y) + (p6.y + p7.y));
    float2 c2 = *(const float2*)&coeffs[((size_t)o * 128 + k) * 128 + lane * 2];
    float v = c2.x * sx + c2.y * sy;
#pragma unroll
    for (int s = 32; s >= 1; s >>= 1) v += __shfl_xor(v, s);
    if (lane == 0) {
        unsigned short hi = f2bf(v);
        unsigned short lo = f2bf(v - bf2f(hi));
        int idx = ((o >> 4) * 4 + (k >> 5)) * 512 + (((k >> 3) & 3) * 16 + (o & 15)) * 8 + (k & 7);
        afrag_hi[idx] = hi;
        afrag_lo[idx] = lo;
    }
}

// ---------------- Kernel C1 (MFMA v2): 64n x 128o tile via bf16x2 split.
// 512 threads = 8 waves; wave w owns o in [w*16, w*16+16), all 64 n.
// Staging: thread (n=tid&63, k-octet base tid>>6) loads 2x(2 float4), splits,
// writes b128 full j-runs with swizzle slot'=(n&15)^(T&3). Reads use same swizzle.
__global__ __launch_bounds__(512) void kC1(const float* __restrict__ U,
                                           const unsigned short* __restrict__ afrag_hi,
                                           const unsigned short* __restrict__ afrag_lo,
                                           float* __restrict__ out,
                                           float* __restrict__ m_part,
                                           float* __restrict__ l_part) {
    __shared__ unsigned short Bh[8192];   // granule*8 + j; granule = T*64 + kq*16 + ((n&15)^(T&3))
    __shared__ unsigned short Bl[8192];
    const int tid = threadIdx.x;
    const int b = blockIdx.x;
    const int n0 = b * TILE_N;
    const int lane = tid & 63;
    const int w = tid >> 6;        // wave id 0..7 -> o base w*16
    const int quad = lane >> 4;    // 0..3
    const int nl = lane & 15;      // col lane

    // ---- stage U -> bf16 hi/lo B-fragments in LDS
    {
        const int sn = tid & 63;        // row within tile
        const int k8b = tid >> 6;       // k-octet base 0..7
        const int gn = n0 + sn;
#pragma unroll
        for (int r = 0; r < 2; ++r) {
            const int k0 = (k8b + r * 8) * 8;   // 0..120, mult of 8
            float4 f0 = make_float4(0, 0, 0, 0), f1 = make_float4(0, 0, 0, 0);
            if (gn < N_PTS) {
                f0 = *(const float4*)&U[(size_t)gn * 128 + k0];
                f1 = *(const float4*)&U[(size_t)gn * 128 + k0 + 4];
            }
            float vv[8] = {f0.x, f0.y, f0.z, f0.w, f1.x, f1.y, f1.z, f1.w};
            s16x8 hh, ll;
#pragma unroll
            for (int jj = 0; jj < 8; ++jj) {
                unsigned short h, l;
                split_trunc(vv[jj], h, l);
                hh[jj] = (short)h;
                ll[jj] = (short)l;
            }
            const int T = (k0 >> 5) * 4 + (sn >> 4);   // tile region 0..31
            const int g = T * 64 + ((k0 >> 3) & 3) * 16 + ((sn & 15) ^ (T & 3));
            *(s16x8*)&Bh[g * 8] = hh;
            *(s16x8*)&Bl[g * 8] = ll;
        }
    }

    // ---- A fragments (8 coalesced 16B loads per wave; same for all blocks -> L2)
    s16x8 Ah[4], Al[4];
#pragma unroll
    for (int kc = 0; kc < 4; ++kc) {
        size_t aoff = (size_t)(w * 4 + kc) * 512 + lane * 8;
        Ah[kc] = *(const s16x8*)(afrag_hi + aoff);
        Al[kc] = *(const s16x8*)(afrag_lo + aoff);
    }

    __syncthreads();   // the only barrier

    f32x4 acc[4];
#pragma unroll
    for (int nt = 0; nt < 4; ++nt) acc[nt] = (f32x4)(0.0f);

#pragma unroll
    for (int kc = 0; kc < 4; ++kc) {
#pragma unroll
        for (int nt = 0; nt < 4; ++nt) {
            const int T = kc * 4 + nt;
            const int g = T * 64 + quad * 16 + (nl ^ (T & 3));
            s16x8 bh = *(s16x8*)&Bh[g * 8];
            s16x8 bl = *(s16x8*)&Bl[g * 8];
            acc[nt] = __builtin_amdgcn_mfma_f32_16x16x32_bf16(Ah[kc], bh, acc[nt], 0, 0, 0);
            acc[nt] = __builtin_amdgcn_mfma_f32_16x16x32_bf16(Al[kc], bh, acc[nt], 0, 0, 0);
            acc[nt] = __builtin_amdgcn_mfma_f32_16x16x32_bf16(Ah[kc], bl, acc[nt], 0, 0, 0);
        }
    }

    // ---- OOB guard (lane covers n = n0 + nt*16 + nl)
#pragma unroll
    for (int nt = 0; nt < 4; ++nt) {
        if (n0 + nt * 16 + nl >= N_PTS) {
#pragma unroll
            for (int reg = 0; reg < 4; ++reg) acc[nt][reg] = -3.4e38f;
        }
    }

    // ---- per-o max over 64 n
    float mb[4];
#pragma unroll
    for (int reg = 0; reg < 4; ++reg)
        mb[reg] = fmaxf(fmaxf(acc[0][reg], acc[1][reg]), fmaxf(acc[2][reg], acc[3][reg]));
#pragma unroll
    for (int s = 1; s < 16; s <<= 1) {
#pragma unroll
        for (int reg = 0; reg < 4; ++reg) mb[reg] = fmaxf(mb[reg], __shfl_xor(mb[reg], s));
    }

    // ---- exp in place + store unnormalized
#pragma unroll
    for (int nt = 0; nt < 4; ++nt) {
#pragma unroll
        for (int reg = 0; reg < 4; ++reg) acc[nt][reg] = __expf(acc[nt][reg] - mb[reg]);
        int gn = n0 + nt * 16 + nl;
        if (gn < N_PTS)
            *(f32x4*)&out[(size_t)gn * 128 + w * 16 + quad * 4] = acc[nt];
    }

    // ---- per-o sum
    float ls[4];
#pragma unroll
    for (int reg = 0; reg < 4; ++reg)
        ls[reg] = ((acc[0][reg] + acc[1][reg]) + (acc[2][reg] + acc[3][reg]));
#pragma unroll
    for (int s = 1; s < 16; s <<= 1) {
#pragma unroll
        for (int reg = 0; reg < 4; ++reg) ls[reg] += __shfl_xor(ls[reg], s);
    }

    if (nl == 0) {
#pragma unroll
        for (int reg = 0; reg < 4; ++reg) {
            int o = w * 16 + quad * 4 + reg;
            m_part[(size_t)o * NB1 + b] = mb[reg];
            l_part[(size_t)o * NB1 + b] = ls[reg];
        }
    }
}

// ---------------- Kernel C2: combine (m,l) over blocks; [o][b] layout -> coalesced
__global__ __launch_bounds__(256) void kC2(const float* __restrict__ m_part,
                                           const float* __restrict__ l_part,
                                           float* __restrict__ scale) {
    const int o = blockIdx.x;
    const int tid = threadIdx.x;
    const float* __restrict__ mp = m_part + (size_t)o * NB1;
    const float* __restrict__ lp = l_part + (size_t)o * NB1;
    __shared__ float sm[256];
    float m = -3.4e38f;
    for (int b = tid; b < NB1; b += 256) m = fmaxf(m, mp[b]);
    sm[tid] = m;
    __syncthreads();
    for (int s = 128; s >= 1; s >>= 1) {
        if (tid < s) sm[tid] = fmaxf(sm[tid], sm[tid + s]);
        __syncthreads();
    }
    m = sm[0];
    __syncthreads();
    float l = 0.0f;
    for (int b = tid; b < NB1; b += 256)
        l += lp[b] * __expf(mp[b] - m);
    sm[tid] = l;
    __syncthreads();
    for (int s = 128; s >= 1; s >>= 1) {
        if (tid < s) sm[tid] += sm[tid + s];
        __syncthreads();
    }
    l = sm[0];
    float inv = 1.0f / l;
    for (int b = tid; b < NB1; b += 256)
        scale[(size_t)o * NB1 + b] = __expf(mp[b] - m) * inv;
}

// ---------------- Kernel C3: out[n][o] *= scale[o][n/64]
__global__ __launch_bounds__(256) void kC3(float* __restrict__ out,
                                           const float* __restrict__ scale) {
    const int b = blockIdx.x;
    const int tid = threadIdx.x;
    __shared__ float sc[128];
    if (tid < 128) sc[tid] = scale[(size_t)tid * NB1 + b];
    __syncthreads();
    const int n0 = b * TILE_N;
#pragma unroll
    for (int r = 0; r < 8; ++r) {
        int idx = (r * 256 + tid) * 4;   // [0,8192)
        int n = idx >> 7;
        int o = idx & 127;
        int gn = n0 + n;
        if (gn < N_PTS) {
            float4 v = *(float4*)&out[(size_t)gn * 128 + o];
            v.x *= sc[o];
            v.y *= sc[o + 1];
            v.z *= sc[o + 2];
            v.w *= sc[o + 3];
            *(float4*)&out[(size_t)gn * 128 + o] = v;
        }
    }
}

extern "C" void kernel_launch(void* const* d_in, const int* in_sizes, int n_in,
                              void* d_out, int out_size, void* d_ws, size_t ws_size,
                              hipStream_t stream) {
    const float* x = (const float*)d_in[0];       // (N, 128)
    const float* U = (const float*)d_in[1];       // (N, 128)
    const float* coeffs = (const float*)d_in[2];  // (128, 128, 128)
    float* out = (float*)d_out;                   // (N, 128)

    // workspace layout (float units; keep 16B alignment for frag buffers)
    float* f = (float*)d_ws;
    float* spec = f;                                    // 16384 (unused; layout keeper)
    unsigned short* afrag_hi = (unsigned short*)(f + 16384);   // 16384 bf16 = 8192 f
    unsigned short* afrag_lo = (unsigned short*)(f + 16384 + 8192);
    float* m_part = f + 16384 + 16384;                  // 128*NB1 ([o][b])
    float* l_part = m_part + (size_t)128 * NB1;
    float* scale = l_part + (size_t)128 * NB1;          // 128*NB1
    float* partial2 = scale + (size_t)128 * NB1;        // 8*16384
    float* partialsA = partial2 + 8 * 16384;
    (void)spec;

    size_t fixed_bytes = ((size_t)(16384 * 2) + (size_t)NB1 * 128 * 3 + (size_t)8 * 16384) * 4;
    int nA = 512;
    if (ws_size > fixed_bytes) {
        size_t avail = (ws_size - fixed_bytes) / 65536;   // 64KB per partial
        if ((size_t)nA > avail) nA = (int)avail;
    } else {
        nA = 1;
    }
    if (nA < 1) nA = 1;
    int chunk = (N_PTS + nA - 1) / nA;

    kA<<<nA, 512, 0, stream>>>(U, x, partialsA, chunk);
    kA2a<<<512, 256, 0, stream>>>(partialsA, partial2, nA);
    kB<<<4096, 256, 0, stream>>>(coeffs, partial2, afrag_hi, afrag_lo);
    kC1<<<NB1, 512, 0, stream>>>(U, afrag_hi, afrag_lo, out, m_part, l_part);
    kC2<<<128, 256, 0, stream>>>(m_part, l_part, scale);
    kC3<<<NB1, 256, 0, stream>>>(out, scale);
}

// Round 9
// 204.874 us; speedup vs baseline: 1.0349x; 1.0349x over previous
//
#include <hip/hip_runtime.h>
#include <math.h>

#define N_PTS 100000
#define KDIM 128
#define CDIM 128          // IN_C == OUT_C == 128
#define TILE_N 64
#define NB1 ((N_PTS + TILE_N - 1) / TILE_N)   // 1563 C1 blocks

typedef short s16x8 __attribute__((ext_vector_type(8)));
typedef float f32x4 __attribute__((ext_vector_type(4)));

// round-to-nearest-even float -> bf16 bits
static __device__ __forceinline__ unsigned short f2bf(float f) {
    unsigned int u = __float_as_uint(f);
    unsigned int r = (u + 0x7FFFu + ((u >> 16) & 1u)) >> 16;
    return (unsigned short)r;
}
static __device__ __forceinline__ float bf2f(unsigned short h) {
    return __uint_as_float(((unsigned int)h) << 16);
}

// truncation hi/lo split (cheap; residual error ~2^-16 relative)
static __device__ __forceinline__ void split_trunc(float v, unsigned short& hi, unsigned short& lo) {
    unsigned int u = __float_as_uint(v);
    unsigned int uh = u & 0xFFFF0000u;
    float lf = v - __uint_as_float(uh);
    hi = (unsigned short)(u >> 16);
    lo = (unsigned short)(__float_as_uint(lf) >> 16);
}

// ---------------- Kernel A (MFMA v4, pipelined): partials[b][k][i] = sum_{n in chunk} U[n,k]*x[n,i]
// 512 thr = 8 waves. 32-row sub-chunks, LDS double-buffered (2 x 32 KB).
// Loop body: issue next chunk's global loads -> compute current buffer ->
// split+write other buffer (vmcnt wait overlapped by other waves' MFMA) -> 1 barrier.
// Staging layout = round-7 conflict-free fragment order (granule = T*64 + octet*16 + (c&15)).
__global__ __launch_bounds__(512, 4) void kA(const float* __restrict__ U,
                                             const float* __restrict__ x,
                                             float* __restrict__ partials,
                                             int chunk) {
    // [buf][arr: 0=U_hi 1=U_lo 2=x_hi 3=x_lo][4096 u16]
    __shared__ unsigned short SB[2][4][4096];   // 64 KB total
    const int tid = threadIdx.x;
    const int b = blockIdx.x;
    const int n_begin = b * chunk;
    const int n_end = min(N_PTS, n_begin + chunk);
    const int lane = tid & 63;
    const int w = tid >> 6;             // wave 0..7
    const int mtb = (w & 3) * 2;        // k-tile base: 2 tiles
    const int ntb = (w >> 2) * 4;       // i-tile base: 4 tiles
    const int quad = lane >> 4;
    const int nl = lane & 15;

    // staging role: thread owns channel sc, row octet rq (rows rq*8..+7 of the 32-row chunk)
    const int sc = tid & 127;           // channel 0..127
    const int rq = tid >> 7;            // 0..3
    const int sgran = (sc >> 4) * 64 + rq * 16 + (sc & 15);   // conflict-free granule

    f32x4 acc[2][4];
#pragma unroll
    for (int mi = 0; mi < 2; ++mi)
#pragma unroll
        for (int ni = 0; ni < 4; ++ni) acc[mi][ni] = (f32x4)(0.0f);

    float uv[8], xv[8];

    // prologue: load + stage chunk 0
    {
        const int r0 = n_begin + rq * 8;
#pragma unroll
        for (int jj = 0; jj < 8; ++jj) {
            int gn = r0 + jj;
            bool ok = (gn < n_end);
            uv[jj] = ok ? U[(size_t)gn * 128 + sc] : 0.0f;
            xv[jj] = ok ? x[(size_t)gn * 128 + sc] : 0.0f;
        }
        s16x8 uh, ul, xh, xl;
#pragma unroll
        for (int jj = 0; jj < 8; ++jj) {
            unsigned short h, l;
            split_trunc(uv[jj], h, l);
            uh[jj] = (short)h; ul[jj] = (short)l;
            split_trunc(xv[jj], h, l);
            xh[jj] = (short)h; xl[jj] = (short)l;
        }
        *(s16x8*)&SB[0][0][sgran * 8] = uh;
        *(s16x8*)&SB[0][1][sgran * 8] = ul;
        *(s16x8*)&SB[0][2][sgran * 8] = xh;
        *(s16x8*)&SB[0][3][sgran * 8] = xl;
    }
    __syncthreads();

    const int nIters = (n_end - n_begin + 31) >> 5;
    for (int it = 0; it < nIters; ++it) {
        const bool more = (it + 1 < nIters);
        // ---- issue next chunk's loads (in flight during compute)
        if (more) {
            const int r0 = n_begin + (it + 1) * 32 + rq * 8;
#pragma unroll
            for (int jj = 0; jj < 8; ++jj) {
                int gn = r0 + jj;
                bool ok = (gn < n_end);
                uv[jj] = ok ? U[(size_t)gn * 128 + sc] : 0.0f;
                xv[jj] = ok ? x[(size_t)gn * 128 + sc] : 0.0f;
            }
        }

        // ---- compute from buffer it&1
        {
            const int buf = it & 1;
            s16x8 ah[2], al[2];
#pragma unroll
            for (int mi = 0; mi < 2; ++mi) {
                const int off = ((mtb + mi) * 64 + lane) * 8;
                ah[mi] = *(s16x8*)&SB[buf][0][off];
                al[mi] = *(s16x8*)&SB[buf][1][off];
            }
#pragma unroll
            for (int ni = 0; ni < 4; ++ni) {
                const int off = ((ntb + ni) * 64 + lane) * 8;
                s16x8 bh = *(s16x8*)&SB[buf][2][off];
                s16x8 bl = *(s16x8*)&SB[buf][3][off];
#pragma unroll
                for (int mi = 0; mi < 2; ++mi) {
                    acc[mi][ni] = __builtin_amdgcn_mfma_f32_16x16x32_bf16(ah[mi], bh, acc[mi][ni], 0, 0, 0);
                    acc[mi][ni] = __builtin_amdgcn_mfma_f32_16x16x32_bf16(al[mi], bh, acc[mi][ni], 0, 0, 0);
                    acc[mi][ni] = __builtin_amdgcn_mfma_f32_16x16x32_bf16(ah[mi], bl, acc[mi][ni], 0, 0, 0);
                }
            }
        }

        // ---- split + write next buffer (waits vmcnt; other waves still computing)
        if (more) {
            const int buf = (it + 1) & 1;
            s16x8 uh, ul, xh, xl;
#pragma unroll
            for (int jj = 0; jj < 8; ++jj) {
                unsigned short h, l;
                split_trunc(uv[jj], h, l);
                uh[jj] = (short)h; ul[jj] = (short)l;
                split_trunc(xv[jj], h, l);
                xh[jj] = (short)h; xl[jj] = (short)l;
            }
            *(s16x8*)&SB[buf][0][sgran * 8] = uh;
            *(s16x8*)&SB[buf][1][sgran * 8] = ul;
            *(s16x8*)&SB[buf][2][sgran * 8] = xh;
            *(s16x8*)&SB[buf][3][sgran * 8] = xl;
        }
        __syncthreads();
    }

    // ---- epilogue: partials[b][k][i]; C/D layout: col(i)=nl, row(k)=quad*4+reg
    float* p = partials + (size_t)b * 16384;
#pragma unroll
    for (int mi = 0; mi < 2; ++mi) {
#pragma unroll
        for (int reg = 0; reg < 4; ++reg) {
            int k = (mtb + mi) * 16 + quad * 4 + reg;
#pragma unroll
            for (int ni = 0; ni < 4; ++ni) {
                int i = (ntb + ni) * 16 + nl;
                p[k * 128 + i] = acc[mi][ni][reg];
            }
        }
    }
}

// ---------------- Kernel A2a: partial2[s][j] = sum of partials[b][j] over this s-slice of b
__global__ __launch_bounds__(256) void kA2a(const float* __restrict__ partials,
                                            float* __restrict__ partial2, int nA) {
    const int jc = blockIdx.x >> 3;
    const int s = blockIdx.x & 7;
    const int j = jc * 256 + threadIdx.x;
    const int per = (nA + 7) >> 3;
    int b = s * per;
    const int be = min(b + per, nA);
    float a0 = 0.0f, a1 = 0.0f, a2 = 0.0f, a3 = 0.0f;
    for (; b + 4 <= be; b += 4) {
        a0 += partials[(size_t)(b + 0) * 16384 + j];
        a1 += partials[(size_t)(b + 1) * 16384 + j];
        a2 += partials[(size_t)(b + 2) * 16384 + j];
        a3 += partials[(size_t)(b + 3) * 16384 + j];
    }
    for (; b < be; ++b) a0 += partials[(size_t)b * 16384 + j];
    partial2[(size_t)s * 16384 + j] = (a0 + a1) + (a2 + a3);
}

// ---------------- Kernel B (merged kA2b): mixed[o][k] = sum_i coeffs[o][k][i]*spec[k][i]
// spec[k][i] computed inline as sum_s partial2[s][k*128+i] (L2/L3-hot).
// Emits bf16 hi/lo of mixed in A-FRAGMENT order for kC1.
__global__ __launch_bounds__(256) void kB(const float* __restrict__ coeffs,
                                          const float* __restrict__ partial2,
                                          unsigned short* __restrict__ afrag_hi,
                                          unsigned short* __restrict__ afrag_lo) {
    int wave = (blockIdx.x * 256 + threadIdx.x) >> 6;   // [0, 16384)
    int lane = threadIdx.x & 63;
    int o = wave >> 7;
    int k = wave & 127;
    const int j = k * 128 + lane * 2;
    float2 p0 = *(const float2*)&partial2[j];
    float2 p1 = *(const float2*)&partial2[16384 + j];
    float2 p2 = *(const float2*)&partial2[2 * 16384 + j];
    float2 p3 = *(const float2*)&partial2[3 * 16384 + j];
    float2 p4 = *(const float2*)&partial2[4 * 16384 + j];
    float2 p5 = *(const float2*)&partial2[5 * 16384 + j];
    float2 p6 = *(const float2*)&partial2[6 * 16384 + j];
    float2 p7 = *(const float2*)&partial2[7 * 16384 + j];
    float sx = ((p0.x + p1.x) + (p2.x + p3.x)) + ((p4.x + p5.x) + (p6.x + p7.x));
    float sy = ((p0.y + p1.y) + (p2.y + p3.y)) + ((p4.y + p5.y) + (p6.y + p7.y));
    float2 c2 = *(const float2*)&coeffs[((size_t)o * 128 + k) * 128 + lane * 2];
    float v = c2.x * sx + c2.y * sy;
#pragma unroll
    for (int s = 32; s >= 1; s >>= 1) v += __shfl_xor(v, s);
    if (lane == 0) {
        unsigned short hi = f2bf(v);
        unsigned short lo = f2bf(v - bf2f(hi));
        int idx = ((o >> 4) * 4 + (k >> 5)) * 512 + (((k >> 3) & 3) * 16 + (o & 15)) * 8 + (k & 7);
        afrag_hi[idx] = hi;
        afrag_lo[idx] = lo;
    }
}

// ---------------- Kernel C1 (MFMA v2): 64n x 128o tile via bf16x2 split.
// 512 threads = 8 waves; wave w owns o in [w*16, w*16+16), all 64 n.
__global__ __launch_bounds__(512) void kC1(const float* __restrict__ U,
                                           const unsigned short* __restrict__ afrag_hi,
                                           const unsigned short* __restrict__ afrag_lo,
                                           float* __restrict__ out,
                                           float* __restrict__ m_part,
                                           float* __restrict__ l_part) {
    __shared__ unsigned short Bh[8192];   // granule*8 + j; granule = T*64 + kq*16 + ((n&15)^(T&3))
    __shared__ unsigned short Bl[8192];
    const int tid = threadIdx.x;
    const int b = blockIdx.x;
    const int n0 = b * TILE_N;
    const int lane = tid & 63;
    const int w = tid >> 6;        // wave id 0..7 -> o base w*16
    const int quad = lane >> 4;    // 0..3
    const int nl = lane & 15;      // col lane

    // ---- stage U -> bf16 hi/lo B-fragments in LDS
    {
        const int sn = tid & 63;        // row within tile
        const int k8b = tid >> 6;       // k-octet base 0..7
        const int gn = n0 + sn;
#pragma unroll
        for (int r = 0; r < 2; ++r) {
            const int k0 = (k8b + r * 8) * 8;   // 0..120, mult of 8
            float4 f0 = make_float4(0, 0, 0, 0), f1 = make_float4(0, 0, 0, 0);
            if (gn < N_PTS) {
                f0 = *(const float4*)&U[(size_t)gn * 128 + k0];
                f1 = *(const float4*)&U[(size_t)gn * 128 + k0 + 4];
            }
            float vv[8] = {f0.x, f0.y, f0.z, f0.w, f1.x, f1.y, f1.z, f1.w};
            s16x8 hh, ll;
#pragma unroll
            for (int jj = 0; jj < 8; ++jj) {
                unsigned short h, l;
                split_trunc(vv[jj], h, l);
                hh[jj] = (short)h;
                ll[jj] = (short)l;
            }
            const int T = (k0 >> 5) * 4 + (sn >> 4);   // tile region 0..31
            const int g = T * 64 + ((k0 >> 3) & 3) * 16 + ((sn & 15) ^ (T & 3));
            *(s16x8*)&Bh[g * 8] = hh;
            *(s16x8*)&Bl[g * 8] = ll;
        }
    }

    // ---- A fragments (8 coalesced 16B loads per wave; same for all blocks -> L2)
    s16x8 Ah[4], Al[4];
#pragma unroll
    for (int kc = 0; kc < 4; ++kc) {
        size_t aoff = (size_t)(w * 4 + kc) * 512 + lane * 8;
        Ah[kc] = *(const s16x8*)(afrag_hi + aoff);
        Al[kc] = *(const s16x8*)(afrag_lo + aoff);
    }

    __syncthreads();   // the only barrier

    f32x4 acc[4];
#pragma unroll
    for (int nt = 0; nt < 4; ++nt) acc[nt] = (f32x4)(0.0f);

#pragma unroll
    for (int kc = 0; kc < 4; ++kc) {
#pragma unroll
        for (int nt = 0; nt < 4; ++nt) {
            const int T = kc * 4 + nt;
            const int g = T * 64 + quad * 16 + (nl ^ (T & 3));
            s16x8 bh = *(s16x8*)&Bh[g * 8];
            s16x8 bl = *(s16x8*)&Bl[g * 8];
            acc[nt] = __builtin_amdgcn_mfma_f32_16x16x32_bf16(Ah[kc], bh, acc[nt], 0, 0, 0);
            acc[nt] = __builtin_amdgcn_mfma_f32_16x16x32_bf16(Al[kc], bh, acc[nt], 0, 0, 0);
            acc[nt] = __builtin_amdgcn_mfma_f32_16x16x32_bf16(Ah[kc], bl, acc[nt], 0, 0, 0);
        }
    }

    // ---- OOB guard (lane covers n = n0 + nt*16 + nl)
#pragma unroll
    for (int nt = 0; nt < 4; ++nt) {
        if (n0 + nt * 16 + nl >= N_PTS) {
#pragma unroll
            for (int reg = 0; reg < 4; ++reg) acc[nt][reg] = -3.4e38f;
        }
    }

    // ---- per-o max over 64 n
    float mb[4];
#pragma unroll
    for (int reg = 0; reg < 4; ++reg)
        mb[reg] = fmaxf(fmaxf(acc[0][reg], acc[1][reg]), fmaxf(acc[2][reg], acc[3][reg]));
#pragma unroll
    for (int s = 1; s < 16; s <<= 1) {
#pragma unroll
        for (int reg = 0; reg < 4; ++reg) mb[reg] = fmaxf(mb[reg], __shfl_xor(mb[reg], s));
    }

    // ---- exp in place + store unnormalized
#pragma unroll
    for (int nt = 0; nt < 4; ++nt) {
#pragma unroll
        for (int reg = 0; reg < 4; ++reg) acc[nt][reg] = __expf(acc[nt][reg] - mb[reg]);
        int gn = n0 + nt * 16 + nl;
        if (gn < N_PTS)
            *(f32x4*)&out[(size_t)gn * 128 + w * 16 + quad * 4] = acc[nt];
    }

    // ---- per-o sum
    float ls[4];
#pragma unroll
    for (int reg = 0; reg < 4; ++reg)
        ls[reg] = ((acc[0][reg] + acc[1][reg]) + (acc[2][reg] + acc[3][reg]));
#pragma unroll
    for (int s = 1; s < 16; s <<= 1) {
#pragma unroll
        for (int reg = 0; reg < 4; ++reg) ls[reg] += __shfl_xor(ls[reg], s);
    }

    if (nl == 0) {
#pragma unroll
        for (int reg = 0; reg < 4; ++reg) {
            int o = w * 16 + quad * 4 + reg;
            m_part[(size_t)o * NB1 + b] = mb[reg];
            l_part[(size_t)o * NB1 + b] = ls[reg];
        }
    }
}

// ---------------- Kernel C2: combine (m,l) over blocks; [o][b] layout -> coalesced
__global__ __launch_bounds__(256) void kC2(const float* __restrict__ m_part,
                                           const float* __restrict__ l_part,
                                           float* __restrict__ scale) {
    const int o = blockIdx.x;
    const int tid = threadIdx.x;
    const float* __restrict__ mp = m_part + (size_t)o * NB1;
    const float* __restrict__ lp = l_part + (size_t)o * NB1;
    __shared__ float sm[256];
    float m = -3.4e38f;
    for (int b = tid; b < NB1; b += 256) m = fmaxf(m, mp[b]);
    sm[tid] = m;
    __syncthreads();
    for (int s = 128; s >= 1; s >>= 1) {
        if (tid < s) sm[tid] = fmaxf(sm[tid], sm[tid + s]);
        __syncthreads();
    }
    m = sm[0];
    __syncthreads();
    float l = 0.0f;
    for (int b = tid; b < NB1; b += 256)
        l += lp[b] * __expf(mp[b] - m);
    sm[tid] = l;
    __syncthreads();
    for (int s = 128; s >= 1; s >>= 1) {
        if (tid < s) sm[tid] += sm[tid + s];
        __syncthreads();
    }
    l = sm[0];
    float inv = 1.0f / l;
    for (int b = tid; b < NB1; b += 256)
        scale[(size_t)o * NB1 + b] = __expf(mp[b] - m) * inv;
}

// ---------------- Kernel C3: out[n][o] *= scale[o][n/64]
__global__ __launch_bounds__(256) void kC3(float* __restrict__ out,
                                           const float* __restrict__ scale) {
    const int b = blockIdx.x;
    const int tid = threadIdx.x;
    __shared__ float sc[128];
    if (tid < 128) sc[tid] = scale[(size_t)tid * NB1 + b];
    __syncthreads();
    const int n0 = b * TILE_N;
#pragma unroll
    for (int r = 0; r < 8; ++r) {
        int idx = (r * 256 + tid) * 4;   // [0,8192)
        int n = idx >> 7;
        int o = idx & 127;
        int gn = n0 + n;
        if (gn < N_PTS) {
            float4 v = *(float4*)&out[(size_t)gn * 128 + o];
            v.x *= sc[o];
            v.y *= sc[o + 1];
            v.z *= sc[o + 2];
            v.w *= sc[o + 3];
            *(float4*)&out[(size_t)gn * 128 + o] = v;
        }
    }
}

extern "C" void kernel_launch(void* const* d_in, const int* in_sizes, int n_in,
                              void* d_out, int out_size, void* d_ws, size_t ws_size,
                              hipStream_t stream) {
    const float* x = (const float*)d_in[0];       // (N, 128)
    const float* U = (const float*)d_in[1];       // (N, 128)
    const float* coeffs = (const float*)d_in[2];  // (128, 128, 128)
    float* out = (float*)d_out;                   // (N, 128)

    // workspace layout (float units; keep 16B alignment for frag buffers)
    float* f = (float*)d_ws;
    float* spec = f;                                    // 16384 (unused; layout keeper)
    unsigned short* afrag_hi = (unsigned short*)(f + 16384);   // 16384 bf16 = 8192 f
    unsigned short* afrag_lo = (unsigned short*)(f + 16384 + 8192);
    float* m_part = f + 16384 + 16384;                  // 128*NB1 ([o][b])
    float* l_part = m_part + (size_t)128 * NB1;
    float* scale = l_part + (size_t)128 * NB1;          // 128*NB1
    float* partial2 = scale + (size_t)128 * NB1;        // 8*16384
    float* partialsA = partial2 + 8 * 16384;
    (void)spec;

    size_t fixed_bytes = ((size_t)(16384 * 2) + (size_t)NB1 * 128 * 3 + (size_t)8 * 16384) * 4;
    int nA = 512;
    if (ws_size > fixed_bytes) {
        size_t avail = (ws_size - fixed_bytes) / 65536;   // 64KB per partial
        if ((size_t)nA > avail) nA = (int)avail;
    } else {
        nA = 1;
    }
    if (nA < 1) nA = 1;
    // chunk = multiple of 32 (kA sub-chunk) to avoid padded MFMA iterations
    int chunk = (((N_PTS + nA - 1) / nA) + 31) & ~31;
    int nB = (N_PTS + chunk - 1) / chunk;   // nB <= nA always

    kA<<<nB, 512, 0, stream>>>(U, x, partialsA, chunk);
    kA2a<<<512, 256, 0, stream>>>(partialsA, partial2, nB);
    kB<<<4096, 256, 0, stream>>>(coeffs, partial2, afrag_hi, afrag_lo);
    kC1<<<NB1, 512, 0, stream>>>(U, afrag_hi, afrag_lo, out, m_part, l_part);
    kC2<<<128, 256, 0, stream>>>(m_part, l_part, scale);
    kC3<<<NB1, 256, 0, stream>>>(out, scale);
}